// Round 19
// baseline (111.292 us; speedup 1.0000x reference)
//
#include <hip/hip_runtime.h>
#include <hip/hip_bf16.h>
#include <math.h>

// ---------------- problem constants ----------------
#define NB 4
#define NH 96
#define NW 96
#define ND 768
#define NPIX (NH*NW)          // 9216
#define RR 3
#define NK 49
#define DCC 64                // K per staged chunk (r19: 64, halves barrier count)
#define NCH 12                // 768/64
#define TS 8                  // tile 8x8 pixels
#define HLX 16                // halo width (14 used + 2 pad) — r16 geometry
#define HLY 14                // halo height
#define NVIS (HLX*HLY)        // 224 vis slots
#define RBASE 224             // rubin slots start (slot index)
#define NSLOT 288             // 224 vis + 64 rubin (= 9 exact passes, no divergence)
#define LROW 72               // ushorts per slot (64 bf16 + 8 pad = 144B)
#define NPASS 9               // 288*8/256 — all lanes active every pass
#define TPX 65                // transpose row stride (floats)
#define TBASE 512             // transpose region base (floats)
#define PBASE 4672            // softmax partials base (floats); 4672+1024=5696<=10368
#define TAU 0.1f
#define SCALE 0.03608439182435161f  // 1/sqrt(768)
#define UNI (1.0f/49.0f)

typedef float f32x4 __attribute__((ext_vector_type(4)));
typedef short bfx8 __attribute__((ext_vector_type(8)));

__device__ __forceinline__ unsigned pk2(float lo, float hi) {
  __hip_bfloat162 h = __float22bfloat162_rn(make_float2(lo, hi));  // v_cvt_pk_bf16_f32
  unsigned u; __builtin_memcpy(&u, &h, 4);
  return u;
}

// barrier that waits LDS ops only (no vmcnt drain — prefetch stays in flight)
#define BARRIER() do { asm volatile("s_waitcnt lgkmcnt(0)" ::: "memory"); \
                       __builtin_amdgcn_s_barrier(); } while (0)

// ws layout: dyl, dxl : float [b][NPIX] ; gacc : float [b][49][144]
// out: dra | ddec | conf_local | conf_global[4] | lw

// ---------------- fused kernel: paired-row MFMA correlation + softmax ----------------
// r16 structure with DCC=64 (r19): 12 chunks x {9 prefetched low-half loads +
// 9 fused high-half loads + 18 ds_writes | barrier | 18 ds_reads + 16 MFMAs |
// barrier}. Event count halves vs r16 (24 barriers vs 48); MFMA phase doubles,
// giving the 1-deep prefetch a 2x cover window.
// Register budget (r11/r14 lessons): launch_bounds 2nd arg = min waves/SIMD;
// 3 -> ~170-reg unified cap. Grid caps occupancy at 2.25 blk/CU (9 waves/CU)
// anyway, so (256,3) loses nothing vs (256,4) and avoids the r15 spill.
// Spill signature: VGPR_Count==64 AND WRITE_SIZE >> 1 MB.
__global__ __launch_bounds__(256, 3) void corr_fused(
    const float* __restrict__ rubin, const float* __restrict__ vis,
    float* __restrict__ dyl, float* __restrict__ dxl,
    float* __restrict__ gacc, float* __restrict__ out) {
  __shared__ __align__(16) unsigned short lds[NSLOT*LROW];  // 41,472 B (10368 floats)
  float* ldsf = (float*)lds;
  const int tid = threadIdx.x;

  // ---- XCD-chunked swizzle: 576 blocks = 8 XCD x 72 ----
  const int wg = blockIdx.x;
  const int vs = (wg & 7) * 72 + (wg >> 3);   // bijective
  const int b = vs / 144, t = vs % 144;       // 144 tiles (12x12) per batch
  const int tileY = t / 12, tileX = t % 12;

  const int g8 = tid >> 3, q = tid & 7;       // 32 slots/pass, 8 lanes/slot

  // ---- staging slot -> global element offset (p<7: vis halo, p>=7: rubin) ----
  unsigned voff[NPASS];
  const int lws0 = g8*LROW + q*4;             // pass p at lws0 + p*32*LROW (+32 hi)
  #pragma unroll
  for (int p = 0; p < NPASS; ++p) {
    const int s = p*32 + g8;
    unsigned pix;
    if (p < 7) {                               // vis halo slot: hy=s>>4, hx=s&15
      const int hy = s >> 4, hx = s & 15;
      const int gh = min(max(tileY*TS + hy - RR, 0), NH-1);
      const int gw = min(max(tileX*TS + hx - RR, 0), NW-1);
      pix = (unsigned)(b*NPIX + gh*NW + gw);
    } else {                                   // rubin slot: ridx = s-224
      const int ridx = s - RBASE;
      pix = (unsigned)(b*NPIX + (tileY*TS + (ridx >> 3))*NW + tileX*TS + (ridx & 7));
    }
    voff[p] = pix*ND + (unsigned)(q*4);
  }

  // ---- MFMA addressing ----
  const int lane = tid & 63, wv = tid >> 6;
  const int j15 = lane & 15, kq = lane >> 4;
  const int aOff = (RBASE + wv*16 + j15)*LROW + kq*8;   // rubin rows 2wv,2wv+1
  const int bO = j15*LROW + kq*8;                        // + (2wv+m)*HLX*LROW

  f32x4 acc[8];
  #pragma unroll
  for (int m = 0; m < 8; ++m) acc[m] = (f32x4){0.f,0.f,0.f,0.f};
  float ssq[NPASS];
  #pragma unroll
  for (int p = 0; p < NPASS; ++p) ssq[p] = 0.f;

#define LOADCH(Larr, chv) { \
  _Pragma("unroll") \
  for (int p = 0; p < NPASS; ++p) \
    Larr[p] = (p < 7) ? *(const float4*)(vis   + voff[p] + (chv)*DCC) \
                      : *(const float4*)(rubin + voff[p] + (chv)*DCC); }

  // write phase: low half from prefetch, high half fused load
#define WRITECH(Larr, chv) { \
  _Pragma("unroll") \
  for (int p = 0; p < NPASS; ++p) { \
    const float4 v0 = Larr[p]; \
    const float4 v1 = (p < 7) ? *(const float4*)(vis   + voff[p] + (chv)*DCC + 32) \
                              : *(const float4*)(rubin + voff[p] + (chv)*DCC + 32); \
    ssq[p] += v0.x*v0.x + v0.y*v0.y + v0.z*v0.z + v0.w*v0.w \
            + v1.x*v1.x + v1.y*v1.y + v1.z*v1.z + v1.w*v1.w; \
    *(uint2*)&lds[lws0 + p*32*LROW]      = make_uint2(pk2(v0.x,v0.y), pk2(v0.z,v0.w)); \
    *(uint2*)&lds[lws0 + p*32*LROW + 32] = make_uint2(pk2(v1.x,v1.y), pk2(v1.z,v1.w)); } }

  // ---- 1-deep software pipeline over 12 chunks of K=64 ----
  float4 L[NPASS];
  LOADCH(L, 0);
  for (int ch = 0; ch < NCH; ++ch) {
    if (ch) BARRIER();            // prev chunk's MFMA readers done
    WRITECH(L, ch);
    BARRIER();
    if (ch + 1 < NCH) LOADCH(L, ch + 1);   // in flight during MFMA + next barrier
    const bfx8 A0 = *(const bfx8*)&lds[aOff];
    const bfx8 A1 = *(const bfx8*)&lds[aOff + 32];
    #pragma unroll
    for (int m = 0; m < 8; ++m) {
      const int rb = (2*wv + m)*(HLX*LROW) + bO;
      const bfx8 B0 = *(const bfx8*)&lds[rb];
      const bfx8 B1 = *(const bfx8*)&lds[rb + 32];
      acc[m] = __builtin_amdgcn_mfma_f32_16x16x32_bf16(A0, B0, acc[m], 0, 0, 0);
      acc[m] = __builtin_amdgcn_mfma_f32_16x16x32_bf16(A1, B1, acc[m], 0, 0, 0);
    }
  }
  BARRIER();   // all MFMA LDS reads done before epilogue clobbers lds

  // ---- epilogue phase 1: per-slot sum-of-squares into ldsf[0..287] ----
  #pragma unroll
  for (int p = 0; p < NPASS; ++p) {
    float r = ssq[p];
    r += __shfl_xor(r, 1); r += __shfl_xor(r, 2); r += __shfl_xor(r, 4);
    if (q == 0) ldsf[p*32 + g8] = r;
  }
  BARRIER();

  // ---- epilogue phase 2: scatter C-fragments -> ldsf[TBASE + px*TPX + tap] ----
  // C element (i=kq*4+r, col j15) of acc[m]: out px = wv*16 + i,
  // dyp3 = m - (i>=8), dxp3 = j15 - (i&7).
  #pragma unroll
  for (int m = 0; m < 8; ++m)
    #pragma unroll
    for (int r = 0; r < 4; ++r) {
      const int i = kq*4 + r;
      const int dyp3 = m - (i >> 3);
      const int dxp3 = j15 - (i & 7);
      if (dyp3 >= 0 && dyp3 < 7 && dxp3 >= 0 && dxp3 < 7)
        ldsf[TBASE + (wv*16 + i)*TPX + dyp3*7 + dxp3] = acc[m][r];
    }
  BARRIER();

  // ---- epilogue phase 3: wave-parallel softmax (wave wv owns 12-13 taps) ----
  {
    const int px = lane;                       // transpose index 0..63
    const int ii = px & 15;
    const int rr = 2*(px >> 4) + (ii >> 3), cc = ii & 7;   // tile row/col (8x8)
    const float irf = (SCALE/TAU) / fmaxf(sqrtf(ldsf[RBASE + rr*8 + cc]), 1e-6f);
    const int jstart = wv*12 + (wv > 0 ? 1 : 0);           // 13,12,12,12 taps
    const int jcnt = (wv == 0) ? 13 : 12;
    float tvv[13];
    float mx = -1e30f;
    #pragma unroll
    for (int jj = 0; jj < 13; ++jj) {
      if (jj < jcnt) {
        const int j = jstart + jj;
        const int jy = j / 7, jx = j % 7;
        const float c = ldsf[TBASE + px*TPX + j];
        const float iv = 1.f / fmaxf(sqrtf(ldsf[(rr+jy)*HLX + cc + jx]), 1e-6f);
        const float tv = c * irf * iv;
        tvv[jj] = tv;
        mx = fmaxf(mx, tv);
        float red = tv;                                   // tile-sum for global softmax
        #pragma unroll
        for (int m = 1; m < 64; m <<= 1) red += __shfl_xor(red, m);
        if (lane == 0) gacc[((size_t)b*NK + j)*144 + t] = red;
      } else tvv[jj] = -1e30f;
    }
    float s = 0.f, sy = 0.f, sx = 0.f;
    #pragma unroll
    for (int jj = 0; jj < 13; ++jj) {
      if (jj < jcnt) {
        const int j = jstart + jj;
        const float e = expf(tvv[jj] - mx);
        s += e; sy += e*(float)(j/7 - RR); sx += e*(float)(j%7 - RR);
      }
    }
    float* pp = &ldsf[PBASE + (wv*64 + px)*4];
    pp[0] = mx; pp[1] = s; pp[2] = sy; pp[3] = sx;
  }
  BARRIER();

  // ---- epilogue phase 4: combine wave partials (wave 0), write outputs ----
  if (wv == 0) {
    const int px = lane;
    const int ii = px & 15;
    const int rr = 2*(px >> 4) + (ii >> 3), cc = ii & 7;
    float M[4], S[4], SY[4], SX[4];
    #pragma unroll
    for (int w = 0; w < 4; ++w) {
      const float* pp = &ldsf[PBASE + (w*64 + px)*4];
      M[w] = pp[0]; S[w] = pp[1]; SY[w] = pp[2]; SX[w] = pp[3];
    }
    float m = fmaxf(fmaxf(M[0], M[1]), fmaxf(M[2], M[3]));
    float s = 0.f, sy = 0.f, sx = 0.f;
    #pragma unroll
    for (int w = 0; w < 4; ++w) {
      const float f = expf(M[w] - m);
      s += S[w]*f; sy += SY[w]*f; sx += SX[w]*f;
    }
    const float inv_s = 1.f / s;
    const int n = (tileY*TS + rr)*NW + tileX*TS + cc;
    const int gg = b*NPIX + n;
    dyl[gg] = sy * inv_s;
    dxl[gg] = sx * inv_s;
    out[(size_t)2*NB*NPIX + gg] = inv_s;                       // conf_local
    const float lw = fminf(fmaxf((inv_s - UNI)/(1.f-UNI), 0.f), 1.f);
    out[(size_t)3*NB*NPIX + 4 + gg] = lw;                      // lw
  }
}

// ---------------- kernel E: global softmax (per-block recompute) + blend + smooth ----------------
__global__ __launch_bounds__(256) void smooth_global(
    const float* __restrict__ dyl, const float* __restrict__ dxl,
    const float* __restrict__ gacc, float* __restrict__ out,
    const int* __restrict__ hvisp, const int* __restrict__ wvisp) {
  __shared__ float sh[2];
  const int g = blockIdx.x*256 + threadIdx.x;
  const int b = g / NPIX, n = g % NPIX;
  const int h = n / NW, w = n % NW;

  if (threadIdx.x < 64) {
    const int k = threadIdx.x;
    float t = -1e30f;
    if (k < NK) {
      float ssum = 0.f;
      for (int i = 0; i < 144; ++i) ssum += gacc[((size_t)b*NK + k)*144 + i];
      t = ssum * (1.f / (float)NPIX);
    }
    float m = t;
    #pragma unroll
    for (int msk = 1; msk < 64; msk <<= 1) m = fmaxf(m, __shfl_xor(m, msk));
    const float e = (k < NK) ? expf(t - m) : 0.f;
    const float dyv = (k < NK) ? (float)(k/7 - RR) : 0.f;
    const float dxv = (k < NK) ? (float)(k%7 - RR) : 0.f;
    float s = e, sy = e*dyv, sx = e*dxv;
    #pragma unroll
    for (int msk = 1; msk < 64; msk <<= 1) {
      s  += __shfl_xor(s,  msk);
      sy += __shfl_xor(sy, msk);
      sx += __shfl_xor(sx, msk);
    }
    if (k == 0) {
      out[(size_t)3*NB*NPIX + b] = 1.f / s;   // conf_global
      sh[0] = sy / s;
      sh[1] = sx / s;
    }
  }
  __syncthreads();
  const float dyg = sh[0], dxg = sh[1];

  const float* conf = out + (size_t)2*NB*NPIX;
  float sy = 0.f, sx = 0.f;
  #pragma unroll
  for (int ddy = -1; ddy <= 1; ++ddy)
    #pragma unroll
    for (int ddx = -1; ddx <= 1; ++ddx) {
      const int hh = h + ddy, wc = w + ddx;
      if (hh >= 0 && hh < NH && wc >= 0 && wc < NW) {   // zero padding
        const int q2 = b*NPIX + hh*NW + wc;
        const float cf = conf[q2];
        const float lw = fminf(fmaxf((cf - UNI)/(1.f-UNI), 0.f), 1.f);
        sy += lw*dyl[q2] + (1.f-lw)*dyg;
        sx += lw*dxl[q2] + (1.f-lw)*dxg;
      }
    }
  const float skyy = (float)hvisp[0] * 0.1f / (float)NH;
  const float skyx = (float)wvisp[0] * 0.1f / (float)NW;
  out[g] = sx * (1.f/9.f) * skyx;                     // dra
  out[(size_t)NB*NPIX + g] = sy * (1.f/9.f) * skyy;   // ddec
}

// ---------------- host launch ----------------
extern "C" void kernel_launch(void* const* d_in, const int* in_sizes, int n_in,
                              void* d_out, int out_size, void* d_ws, size_t ws_size,
                              hipStream_t stream) {
  (void)in_sizes; (void)n_in; (void)out_size; (void)ws_size;
  const float* rubin = (const float*)d_in[0];
  const float* vis   = (const float*)d_in[1];
  const int* hvis = (const int*)d_in[4];
  const int* wvis = (const int*)d_in[5];
  float* out = (float*)d_out;

  float* dyl  = (float*)d_ws;                       // NB*NPIX
  float* dxl  = dyl  + (size_t)NB*NPIX;             // NB*NPIX
  float* gacc = dxl  + (size_t)NB*NPIX;             // NB*49*144

  corr_fused<<<dim3(576), 256, 0, stream>>>(rubin, vis, dyl, dxl, gacc, out);
  smooth_global<<<dim3((NB*NPIX)/256), 256, 0, stream>>>(dyl, dxl, gacc, out, hvis, wvis);
}

// Round 20
// 65.811 us; speedup vs baseline: 1.6911x; 1.6911x over previous
//
#include <hip/hip_runtime.h>
#include <hip/hip_bf16.h>
#include <math.h>

// ---------------- problem constants ----------------
#define NB 4
#define NH 96
#define NW 96
#define ND 768
#define NPIX (NH*NW)          // 9216
#define RR 3
#define NK 49
#define DCC 32                // K per staged chunk
#define NCH 24                // 768/32 — full K per block (fused, NS=1)
#define TS 8                  // tile 8x8 pixels
#define HLX 16                // halo width (14 used + 2 pad)
#define HLY 14                // halo height
#define NVIS (HLX*HLY)        // 224 vis slots
#define RBASE 224             // rubin slots start (slot index)
#define NSLOT 288             // 224 vis + 64 rubin (= 9 exact passes)
#define LROW 40               // ushorts per slot (32 bf16 + 8 pad = 80B)
#define NPASS 9               // 288*8/256 — all lanes active every pass
#define TPX 65                // transpose row stride (floats)
#define TBASE 512             // transpose region base (floats)
#define PBASE 4672            // softmax partials base (floats); 4672+1024=5696<=5760
#define TAU 0.1f
#define SCALE 0.03608439182435161f  // 1/sqrt(768)
#define UNI (1.0f/49.0f)

typedef float f32x4 __attribute__((ext_vector_type(4)));
typedef short bfx8 __attribute__((ext_vector_type(8)));

__device__ __forceinline__ unsigned pk2(float lo, float hi) {
  __hip_bfloat162 h = __float22bfloat162_rn(make_float2(lo, hi));  // v_cvt_pk_bf16_f32
  unsigned u; __builtin_memcpy(&u, &h, 4);
  return u;
}

// barrier that waits LDS ops only (no vmcnt drain — prefetch stays in flight)
#define BARRIER() do { asm volatile("s_waitcnt lgkmcnt(0)" ::: "memory"); \
                       __builtin_amdgcn_s_barrier(); } while (0)

// ws layout: dyl, dxl : float [b][NPIX] ; gacc : float [b][49][144]
// out: dra | ddec | conf_local | conf_global[4] | lw

// ---------------- fused kernel: paired-row MFMA correlation + softmax ----------------
// MEASURED BEST (r16: 65.5 us total). Do not perturb without a within-probe A/B:
//  - NS=2 TLP boost (r17): occupancy +35% -> corr unchanged, downstream +7us. WORSE.
//  - packed HLX=14 (r18): volume -10% -> divergent staging, corr +22%. WORSE.
//  - DCC=64 (r19): barriers -50% -> exposed hi-half load latency, corr +49%. WORSE.
// corr is a balanced latency/LDS/L2 local optimum at 9 waves/CU (grid 576 = 2.25
// blocks/CU; register file would allow 4).
// MFMA scheme: 8x8 tile, wave wv owns rows {2wv, 2wv+1}. A-frag j<8 -> (row 2wv,
// x=j), j>=8 -> (row 2wv+1, x=j-8). One B-row fragment (16 cols, 14 used) covers
// the dx band of BOTH halves -> 8 MFMAs/chunk, acc = 8 f32x4 = 32 AGPRs.
// Register quantum (m69): 64 VGPR + 32 AGPR = 96 unified -> 4 waves/SIMD fits.
// Spill signature: VGPR_Count==64 + WRITE_SIZE >> 1 MB (r8/r11/r15/r19).
__global__ __launch_bounds__(256, 4) void corr_fused(
    const float* __restrict__ rubin, const float* __restrict__ vis,
    float* __restrict__ dyl, float* __restrict__ dxl,
    float* __restrict__ gacc, float* __restrict__ out) {
  __shared__ __align__(16) unsigned short lds[NSLOT*LROW];  // 23,040 B (5760 floats)
  float* ldsf = (float*)lds;
  const int tid = threadIdx.x;

  // ---- XCD-chunked swizzle: 576 blocks = 8 XCD x 72 ----
  const int wg = blockIdx.x;
  const int vs = (wg & 7) * 72 + (wg >> 3);   // bijective
  const int b = vs / 144, t = vs % 144;       // 144 tiles (12x12) per batch
  const int tileY = t / 12, tileX = t % 12;

  const int g8 = tid >> 3, q = tid & 7;       // 32 slots/pass, 8 lanes/slot

  // ---- staging slot -> global element offset (p<7: vis halo, p>=7: rubin) ----
  unsigned voff[NPASS];
  const int lws0 = g8*LROW + q*4;             // pass p at lws0 + p*32*LROW
  #pragma unroll
  for (int p = 0; p < NPASS; ++p) {
    const int s = p*32 + g8;
    unsigned pix;
    if (p < 7) {                               // vis halo slot: hy=s>>4, hx=s&15
      const int hy = s >> 4, hx = s & 15;
      const int gh = min(max(tileY*TS + hy - RR, 0), NH-1);
      const int gw = min(max(tileX*TS + hx - RR, 0), NW-1);
      pix = (unsigned)(b*NPIX + gh*NW + gw);
    } else {                                   // rubin slot: ridx = s-224
      const int ridx = s - RBASE;
      pix = (unsigned)(b*NPIX + (tileY*TS + (ridx >> 3))*NW + tileX*TS + (ridx & 7));
    }
    voff[p] = pix*ND + (unsigned)(q*4);
  }

  // ---- MFMA addressing ----
  const int lane = tid & 63, wv = tid >> 6;
  const int j15 = lane & 15, kq = lane >> 4;
  const int aOff = (RBASE + wv*16 + j15)*LROW + kq*8;   // rubin rows 2wv,2wv+1
  const int bO = j15*LROW + kq*8;                        // + (2wv+m)*HLX*LROW

  f32x4 acc[8];
  #pragma unroll
  for (int m = 0; m < 8; ++m) acc[m] = (f32x4){0.f,0.f,0.f,0.f};
  float ssq[NPASS];
  #pragma unroll
  for (int p = 0; p < NPASS; ++p) ssq[p] = 0.f;

#define LOADCH(Larr, chv) { \
  _Pragma("unroll") \
  for (int p = 0; p < NPASS; ++p) \
    Larr[p] = (p < 7) ? *(const float4*)(vis   + voff[p] + (chv)*DCC) \
                      : *(const float4*)(rubin + voff[p] + (chv)*DCC); }

#define WRITECH(Larr) { \
  _Pragma("unroll") \
  for (int p = 0; p < NPASS; ++p) { \
    const float4 v = Larr[p]; \
    ssq[p] += v.x*v.x + v.y*v.y + v.z*v.z + v.w*v.w; \
    *(uint2*)&lds[lws0 + p*32*LROW] = make_uint2(pk2(v.x,v.y), pk2(v.z,v.w)); } }

  // ---- 1-deep software pipeline (r13 structure) ----
  float4 L[NPASS];
  LOADCH(L, 0);
  for (int ch = 0; ch < NCH; ++ch) {
    if (ch) BARRIER();            // prev chunk's MFMA readers done
    WRITECH(L);
    BARRIER();
    if (ch + 1 < NCH) LOADCH(L, ch + 1);   // in flight during MFMA + next barrier
    const bfx8 A = *(const bfx8*)&lds[aOff];
    #pragma unroll
    for (int m = 0; m < 8; ++m) {
      const bfx8 B = *(const bfx8*)&lds[(2*wv + m)*(HLX*LROW) + bO];
      acc[m] = __builtin_amdgcn_mfma_f32_16x16x32_bf16(A, B, acc[m], 0, 0, 0);
    }
  }
  BARRIER();   // all MFMA LDS reads done before epilogue clobbers lds

  // ---- epilogue phase 1: per-slot sum-of-squares into ldsf[0..287] ----
  #pragma unroll
  for (int p = 0; p < NPASS; ++p) {
    float r = ssq[p];
    r += __shfl_xor(r, 1); r += __shfl_xor(r, 2); r += __shfl_xor(r, 4);
    if (q == 0) ldsf[p*32 + g8] = r;
  }
  BARRIER();

  // ---- epilogue phase 2: scatter C-fragments -> ldsf[TBASE + px*TPX + tap] ----
  // C element (i=kq*4+r, col j15) of acc[m]: out pixel px = wv*16 + i,
  // dyp3 = m - (i>=8), dxp3 = j15 - (i&7).
  #pragma unroll
  for (int m = 0; m < 8; ++m)
    #pragma unroll
    for (int r = 0; r < 4; ++r) {
      const int i = kq*4 + r;
      const int dyp3 = m - (i >> 3);
      const int dxp3 = j15 - (i & 7);
      if (dyp3 >= 0 && dyp3 < 7 && dxp3 >= 0 && dxp3 < 7)
        ldsf[TBASE + (wv*16 + i)*TPX + dyp3*7 + dxp3] = acc[m][r];
    }
  BARRIER();

  // ---- epilogue phase 3: wave-parallel softmax (wave wv owns 12-13 taps) ----
  {
    const int px = lane;                       // transpose index 0..63
    const int ii = px & 15;
    const int rr = 2*(px >> 4) + (ii >> 3), cc = ii & 7;   // tile row/col (8x8)
    const float irf = (SCALE/TAU) / fmaxf(sqrtf(ldsf[RBASE + rr*8 + cc]), 1e-6f);
    const int jstart = wv*12 + (wv > 0 ? 1 : 0);           // 13,12,12,12 taps
    const int jcnt = (wv == 0) ? 13 : 12;
    float tvv[13];
    float mx = -1e30f;
    #pragma unroll
    for (int jj = 0; jj < 13; ++jj) {
      if (jj < jcnt) {
        const int j = jstart + jj;
        const int jy = j / 7, jx = j % 7;
        const float c = ldsf[TBASE + px*TPX + j];
        const float iv = 1.f / fmaxf(sqrtf(ldsf[(rr+jy)*HLX + cc + jx]), 1e-6f);
        const float tv = c * irf * iv;
        tvv[jj] = tv;
        mx = fmaxf(mx, tv);
        float red = tv;                                   // tile-sum for global softmax
        #pragma unroll
        for (int m = 1; m < 64; m <<= 1) red += __shfl_xor(red, m);
        if (lane == 0) gacc[((size_t)b*NK + j)*144 + t] = red;
      } else tvv[jj] = -1e30f;
    }
    float s = 0.f, sy = 0.f, sx = 0.f;
    #pragma unroll
    for (int jj = 0; jj < 13; ++jj) {
      if (jj < jcnt) {
        const int j = jstart + jj;
        const float e = expf(tvv[jj] - mx);
        s += e; sy += e*(float)(j/7 - RR); sx += e*(float)(j%7 - RR);
      }
    }
    float* pp = &ldsf[PBASE + (wv*64 + px)*4];
    pp[0] = mx; pp[1] = s; pp[2] = sy; pp[3] = sx;
  }
  BARRIER();

  // ---- epilogue phase 4: combine wave partials (wave 0), write outputs ----
  if (wv == 0) {
    const int px = lane;
    const int ii = px & 15;
    const int rr = 2*(px >> 4) + (ii >> 3), cc = ii & 7;
    float M[4], S[4], SY[4], SX[4];
    #pragma unroll
    for (int w = 0; w < 4; ++w) {
      const float* pp = &ldsf[PBASE + (w*64 + px)*4];
      M[w] = pp[0]; S[w] = pp[1]; SY[w] = pp[2]; SX[w] = pp[3];
    }
    float m = fmaxf(fmaxf(M[0], M[1]), fmaxf(M[2], M[3]));
    float s = 0.f, sy = 0.f, sx = 0.f;
    #pragma unroll
    for (int w = 0; w < 4; ++w) {
      const float f = expf(M[w] - m);
      s += S[w]*f; sy += SY[w]*f; sx += SX[w]*f;
    }
    const float inv_s = 1.f / s;
    const int n = (tileY*TS + rr)*NW + tileX*TS + cc;
    const int gg = b*NPIX + n;
    dyl[gg] = sy * inv_s;
    dxl[gg] = sx * inv_s;
    out[(size_t)2*NB*NPIX + gg] = inv_s;                       // conf_local
    const float lw = fminf(fmaxf((inv_s - UNI)/(1.f-UNI), 0.f), 1.f);
    out[(size_t)3*NB*NPIX + 4 + gg] = lw;                      // lw
  }
}

// ---------------- kernel E: global softmax (per-block recompute) + blend + smooth ----------------
__global__ __launch_bounds__(256) void smooth_global(
    const float* __restrict__ dyl, const float* __restrict__ dxl,
    const float* __restrict__ gacc, float* __restrict__ out,
    const int* __restrict__ hvisp, const int* __restrict__ wvisp) {
  __shared__ float sh[2];
  const int g = blockIdx.x*256 + threadIdx.x;
  const int b = g / NPIX, n = g % NPIX;
  const int h = n / NW, w = n % NW;

  if (threadIdx.x < 64) {
    const int k = threadIdx.x;
    float t = -1e30f;
    if (k < NK) {
      float ssum = 0.f;
      for (int i = 0; i < 144; ++i) ssum += gacc[((size_t)b*NK + k)*144 + i];
      t = ssum * (1.f / (float)NPIX);
    }
    float m = t;
    #pragma unroll
    for (int msk = 1; msk < 64; msk <<= 1) m = fmaxf(m, __shfl_xor(m, msk));
    const float e = (k < NK) ? expf(t - m) : 0.f;
    const float dyv = (k < NK) ? (float)(k/7 - RR) : 0.f;
    const float dxv = (k < NK) ? (float)(k%7 - RR) : 0.f;
    float s = e, sy = e*dyv, sx = e*dxv;
    #pragma unroll
    for (int msk = 1; msk < 64; msk <<= 1) {
      s  += __shfl_xor(s,  msk);
      sy += __shfl_xor(sy, msk);
      sx += __shfl_xor(sx, msk);
    }
    if (k == 0) {
      out[(size_t)3*NB*NPIX + b] = 1.f / s;   // conf_global
      sh[0] = sy / s;
      sh[1] = sx / s;
    }
  }
  __syncthreads();
  const float dyg = sh[0], dxg = sh[1];

  const float* conf = out + (size_t)2*NB*NPIX;
  float sy = 0.f, sx = 0.f;
  #pragma unroll
  for (int ddy = -1; ddy <= 1; ++ddy)
    #pragma unroll
    for (int ddx = -1; ddx <= 1; ++ddx) {
      const int hh = h + ddy, wc = w + ddx;
      if (hh >= 0 && hh < NH && wc >= 0 && wc < NW) {   // zero padding
        const int q2 = b*NPIX + hh*NW + wc;
        const float cf = conf[q2];
        const float lw = fminf(fmaxf((cf - UNI)/(1.f-UNI), 0.f), 1.f);
        sy += lw*dyl[q2] + (1.f-lw)*dyg;
        sx += lw*dxl[q2] + (1.f-lw)*dxg;
      }
    }
  const float skyy = (float)hvisp[0] * 0.1f / (float)NH;
  const float skyx = (float)wvisp[0] * 0.1f / (float)NW;
  out[g] = sx * (1.f/9.f) * skyx;                     // dra
  out[(size_t)NB*NPIX + g] = sy * (1.f/9.f) * skyy;   // ddec
}

// ---------------- host launch ----------------
extern "C" void kernel_launch(void* const* d_in, const int* in_sizes, int n_in,
                              void* d_out, int out_size, void* d_ws, size_t ws_size,
                              hipStream_t stream) {
  (void)in_sizes; (void)n_in; (void)out_size; (void)ws_size;
  const float* rubin = (const float*)d_in[0];
  const float* vis   = (const float*)d_in[1];
  const int* hvis = (const int*)d_in[4];
  const int* wvis = (const int*)d_in[5];
  float* out = (float*)d_out;

  float* dyl  = (float*)d_ws;                       // NB*NPIX
  float* dxl  = dyl  + (size_t)NB*NPIX;             // NB*NPIX
  float* gacc = dxl  + (size_t)NB*NPIX;             // NB*49*144

  corr_fused<<<dim3(576), 256, 0, stream>>>(rubin, vis, dyl, dxl, gacc, out);
  smooth_global<<<dim3((NB*NPIX)/256), 256, 0, stream>>>(dyl, dxl, gacc, out, hvis, wvis);
}